// Round 1
// baseline (19.628 us; speedup 1.0000x reference)
//
#include <hip/hip_runtime.h>
#include <hip/hip_bf16.h>
#include <math.h>

// DTLN part-2 inference: enc matvec -> global LN -> LSTM1 -> LSTM2 -> dense mask -> dec matvec
// All fp32. Latency-bound; 5-stage kernel pipeline with redundant cheap prologues.

#define FRAME 1024
#define ENC 256
#define HID 128

__device__ __forceinline__ float wave_reduce(float v) {
#pragma unroll
    for (int o = 32; o > 0; o >>= 1) v += __shfl_down(v, o);
    return v;  // valid on lane 0 of each wave
}

__device__ __forceinline__ float sigmoidf(float x) { return 1.0f / (1.0f + expf(-x)); }

// K1: enc = enc_W @ y1   (256 rows x 1024)
__global__ __launch_bounds__(256) void k_enc(const float* __restrict__ W,
                                             const float* __restrict__ y,
                                             float* __restrict__ enc) {
    const int row = blockIdx.x;
    const int t = threadIdx.x;
    const int lane = t & 63, wid = t >> 6;
    const float4 a = reinterpret_cast<const float4*>(W + row * FRAME)[t];
    const float4 b = reinterpret_cast<const float4*>(y)[t];
    float p = a.x * b.x + a.y * b.y + a.z * b.z + a.w * b.w;
    p = wave_reduce(p);
    __shared__ float red[4];
    if (lane == 0) red[wid] = p;
    __syncthreads();
    if (t == 0) enc[row] = red[0] + red[1] + red[2] + red[3];
}

// K2: per-block redundant LN stats + enc_norm, then 4 waves x 128 blocks = 512 z1 rows
__global__ __launch_bounds__(256) void k_ln_lstm1(const float* __restrict__ enc,
                                                  const float* __restrict__ gamma,
                                                  const float* __restrict__ beta,
                                                  const float* __restrict__ Wih1,
                                                  const float* __restrict__ Whh1,
                                                  const float* __restrict__ bih1,
                                                  const float* __restrict__ bhh1,
                                                  const float* __restrict__ h1_in,
                                                  float* __restrict__ z1) {
    __shared__ __align__(16) float encn[ENC];
    __shared__ __align__(16) float hsh[HID];
    __shared__ float red[8];
    const int t = threadIdx.x;
    const int lane = t & 63, wid = t >> 6;

    const float e = enc[t];
    float s = wave_reduce(e);
    float s2 = wave_reduce(e * e);
    if (lane == 0) { red[wid] = s; red[4 + wid] = s2; }
    if (t < HID) hsh[t] = h1_in[t];
    __syncthreads();
    const float sum = red[0] + red[1] + red[2] + red[3];
    const float sumsq = red[4] + red[5] + red[6] + red[7];
    const float mean = sum * (1.0f / ENC);
    const float var = sumsq * (1.0f / ENC) - mean * mean;
    const float inv = rsqrtf(var + 1e-7f);
    encn[t] = (e - mean) * inv * gamma[t] + beta[t];
    __syncthreads();

    const int row = blockIdx.x * 4 + wid;  // 512 rows
    const float4 a = reinterpret_cast<const float4*>(Wih1 + row * ENC)[lane];
    const float4 b = reinterpret_cast<const float4*>(encn)[lane];
    float p = a.x * b.x + a.y * b.y + a.z * b.z + a.w * b.w;
    const float2 c = reinterpret_cast<const float2*>(Whh1 + row * HID)[lane];
    const float2 d = reinterpret_cast<const float2*>(hsh)[lane];
    p += c.x * d.x + c.y * d.y;
    p = wave_reduce(p);
    if (lane == 0) z1[row] = p + bih1[row] + bhh1[row];
}

// K3: redundant LSTM1 gates -> h1 in LDS; 512 z2 rows; block 0 writes h1/c1
__global__ __launch_bounds__(256) void k_lstm2(const float* __restrict__ z1,
                                               const float* __restrict__ c1_in,
                                               const float* __restrict__ h2_in,
                                               const float* __restrict__ Wih2,
                                               const float* __restrict__ Whh2,
                                               const float* __restrict__ bih2,
                                               const float* __restrict__ bhh2,
                                               float* __restrict__ z2,
                                               float* __restrict__ out_h1,
                                               float* __restrict__ out_c1) {
    __shared__ __align__(16) float h1s[HID];
    __shared__ __align__(16) float h2s[HID];
    const int t = threadIdx.x;
    const int lane = t & 63, wid = t >> 6;
    if (t < HID) {
        const float i = sigmoidf(z1[t]);
        const float f = sigmoidf(z1[HID + t]);
        const float g = tanhf(z1[2 * HID + t]);
        const float o = sigmoidf(z1[3 * HID + t]);
        const float c = f * c1_in[t] + i * g;
        const float h = o * tanhf(c);
        h1s[t] = h;
        h2s[t] = h2_in[t];
        if (blockIdx.x == 0) { out_h1[t] = h; out_c1[t] = c; }
    }
    __syncthreads();

    const int row = blockIdx.x * 4 + wid;  // 512 rows
    const float2 a = reinterpret_cast<const float2*>(Wih2 + row * HID)[lane];
    const float2 b = reinterpret_cast<const float2*>(h1s)[lane];
    const float2 c = reinterpret_cast<const float2*>(Whh2 + row * HID)[lane];
    const float2 d = reinterpret_cast<const float2*>(h2s)[lane];
    float p = a.x * b.x + a.y * b.y + c.x * d.x + c.y * d.y;
    p = wave_reduce(p);
    if (lane == 0) z2[row] = p + bih2[row] + bhh2[row];
}

// K4: redundant LSTM2 gates -> h2; 256 mask rows -> estimated; block 0 writes h2/c2
__global__ __launch_bounds__(256) void k_mask(const float* __restrict__ z2,
                                              const float* __restrict__ c2_in,
                                              const float* __restrict__ dense_W,
                                              const float* __restrict__ dense_b,
                                              const float* __restrict__ enc,
                                              float* __restrict__ est,
                                              float* __restrict__ out_h2,
                                              float* __restrict__ out_c2) {
    __shared__ __align__(16) float h2sh[HID];
    const int t = threadIdx.x;
    const int lane = t & 63, wid = t >> 6;
    if (t < HID) {
        const float i = sigmoidf(z2[t]);
        const float f = sigmoidf(z2[HID + t]);
        const float g = tanhf(z2[2 * HID + t]);
        const float o = sigmoidf(z2[3 * HID + t]);
        const float c = f * c2_in[t] + i * g;
        const float h = o * tanhf(c);
        h2sh[t] = h;
        if (blockIdx.x == 0) { out_h2[t] = h; out_c2[t] = c; }
    }
    __syncthreads();

    const int row = blockIdx.x * 4 + wid;  // 256 rows
    const float2 a = reinterpret_cast<const float2*>(dense_W + row * HID)[lane];
    const float2 b = reinterpret_cast<const float2*>(h2sh)[lane];
    float p = a.x * b.x + a.y * b.y;
    p = wave_reduce(p);
    if (lane == 0) {
        const float m = sigmoidf(p + dense_b[row]);
        est[row] = m * enc[row];
    }
}

// K5: decoded = dec_W @ estimated  (1024 rows x 256)
__global__ __launch_bounds__(256) void k_dec(const float* __restrict__ dec_W,
                                             const float* __restrict__ est,
                                             float* __restrict__ out) {
    __shared__ __align__(16) float es[ENC];
    const int t = threadIdx.x;
    const int lane = t & 63, wid = t >> 6;
    es[t] = est[t];
    __syncthreads();
    const int row = blockIdx.x * 4 + wid;  // 1024 rows
    const float4 a = reinterpret_cast<const float4*>(dec_W + row * ENC)[lane];
    const float4 b = reinterpret_cast<const float4*>(es)[lane];
    float p = a.x * b.x + a.y * b.y + a.z * b.z + a.w * b.w;
    p = wave_reduce(p);
    if (lane == 0) out[row] = p;
}

extern "C" void kernel_launch(void* const* d_in, const int* in_sizes, int n_in,
                              void* d_out, int out_size, void* d_ws, size_t ws_size,
                              hipStream_t stream) {
    const float* y1      = (const float*)d_in[0];
    const float* h1_in   = (const float*)d_in[1];
    const float* c1_in   = (const float*)d_in[2];
    const float* h2_in   = (const float*)d_in[3];
    const float* c2_in   = (const float*)d_in[4];
    const float* enc_W   = (const float*)d_in[5];
    const float* gamma   = (const float*)d_in[6];
    const float* beta    = (const float*)d_in[7];
    const float* Wih1    = (const float*)d_in[8];
    const float* Whh1    = (const float*)d_in[9];
    const float* bih1    = (const float*)d_in[10];
    const float* bhh1    = (const float*)d_in[11];
    const float* Wih2    = (const float*)d_in[12];
    const float* Whh2    = (const float*)d_in[13];
    const float* bih2    = (const float*)d_in[14];
    const float* bhh2    = (const float*)d_in[15];
    const float* dense_W = (const float*)d_in[16];
    const float* dense_b = (const float*)d_in[17];
    const float* dec_W   = (const float*)d_in[18];

    float* out = (float*)d_out;
    float* ws  = (float*)d_ws;
    float* enc = ws;          // 256
    float* z1  = ws + 256;    // 512
    float* z2  = ws + 768;    // 512
    float* est = ws + 1280;   // 256

    k_enc<<<256, 256, 0, stream>>>(enc_W, y1, enc);
    k_ln_lstm1<<<128, 256, 0, stream>>>(enc, gamma, beta, Wih1, Whh1, bih1, bhh1, h1_in, z1);
    k_lstm2<<<128, 256, 0, stream>>>(z1, c1_in, h2_in, Wih2, Whh2, bih2, bhh2, z2,
                                     out + FRAME, out + FRAME + HID);
    k_mask<<<64, 256, 0, stream>>>(z2, c2_in, dense_W, dense_b, enc, est,
                                   out + FRAME + 2 * HID, out + FRAME + 3 * HID);
    k_dec<<<256, 256, 0, stream>>>(dec_W, est, out);
}